// Round 1
// baseline (367.518 us; speedup 1.0000x reference)
//
#include <hip/hip_runtime.h>
#include <hip/hip_bf16.h>
#include <stdint.h>

using bf16 = __hip_bfloat16;
typedef __bf16 bf16x8 __attribute__((ext_vector_type(8)));
typedef float f32x4 __attribute__((ext_vector_type(4)));
typedef short short8 __attribute__((ext_vector_type(8)));

#define GLD_LDS16(gp, lp)                                                            \
  __builtin_amdgcn_global_load_lds(                                                  \
      (const __attribute__((address_space(1))) unsigned int*)(gp),                   \
      (__attribute__((address_space(3))) unsigned int*)(lp), 16, 0, 0)

// ---------------- x (f32) -> bf16 ----------------
__global__ __launch_bounds__(256) void convert_x_kernel(const float* __restrict__ x,
                                                        bf16* __restrict__ xb, int n)
{
  for (int i = (blockIdx.x * 256 + threadIdx.x) * 8; i < n; i += gridDim.x * 256 * 8) {
    float4 a = *(const float4*)(x + i);
    float4 b = *(const float4*)(x + i + 4);
    union { bf16 h[8]; short8 v; } u;
    u.h[0] = __float2bfloat16(a.x);
    u.h[1] = __float2bfloat16(a.y);
    u.h[2] = __float2bfloat16(a.z);
    u.h[3] = __float2bfloat16(a.w);
    u.h[4] = __float2bfloat16(b.x);
    u.h[5] = __float2bfloat16(b.y);
    u.h[6] = __float2bfloat16(b.z);
    u.h[7] = __float2bfloat16(b.w);
    *(short8*)(xb + i) = u.v;
  }
}

// ---------------- U -> bf16, SVtT[i][r] = S[r]*Vt[r][i] (bf16) ----------------
__global__ __launch_bounds__(256) void prep_kernel(const float* __restrict__ U,
                                                   const float* __restrict__ S,
                                                   const float* __restrict__ Vt,
                                                   bf16* __restrict__ Ub,
                                                   bf16* __restrict__ SVtT)
{
  int t = blockIdx.x * 256 + threadIdx.x;   // total 4096*128 = 524288 threads
  if (t < 4096 * 128) {
    Ub[t] = __float2bfloat16(U[t]);
    int i = t >> 7, r = t & 127;
    SVtT[t] = __float2bfloat16(S[r] * Vt[r * 4096 + i]);
  }
}

// ---------------- 128x128x32 MFMA GEMM, C[m][n] = sum_k A[m][k]*B[n][k] ----------------
// EPI==0: C_f32[m][n] = acc + bias[n]          (main GEMM)
// EPI==1: Cb_bf16[m][n] = acc + codebook-dequant(m,n)   (lowrank+dequant GEMM)
template <int EPI>
__global__ __launch_bounds__(256, 2) void gemm_bt(const bf16* __restrict__ A,
                                                  const bf16* __restrict__ B,
                                                  float* __restrict__ C,
                                                  bf16* __restrict__ Cb,
                                                  int M, int N, int K,
                                                  const float* __restrict__ bias,
                                                  const int* __restrict__ indices,
                                                  const float* __restrict__ centroids,
                                                  const float* __restrict__ wscale,
                                                  const float* __restrict__ wbias)
{
  __shared__ bf16 As[128 * 32];
  __shared__ bf16 Bs[128 * 32];

  const int tid  = threadIdx.x;
  const int m0   = blockIdx.y * 128;
  const int n0   = blockIdx.x * 128;
  const int wid  = tid >> 6;
  const int lane = tid & 63;
  const int wm   = wid >> 1;   // 0..1
  const int wn   = wid & 1;    // 0..1

  f32x4 acc[4][4] = {};

  // staging: thread t covers LDS flat elems [t*8, t*8+8) (issue 0) and +2048 (issue 1)
  const int sr = tid >> 2;          // 0..63
  const int sc = (tid & 3) * 8;     // 0,8,16,24
  const bf16* ga = A + (size_t)(m0 + sr) * K + sc;
  const bf16* gb = B + (size_t)(n0 + sr) * K + sc;
  bf16* la = &As[tid * 8];
  bf16* lb = &Bs[tid * 8];
  const size_t rowHop = (size_t)64 * K;   // +64 rows

  const int kk   = (lane >> 4) * 8;   // k-chunk within BK=32
  const int fr   = lane & 15;         // fragment row/col

  for (int kt = 0; kt < K; kt += 32) {
    GLD_LDS16(ga + kt,          la);
    GLD_LDS16(ga + kt + rowHop, la + 2048);
    GLD_LDS16(gb + kt,          lb);
    GLD_LDS16(gb + kt + rowHop, lb + 2048);
    __syncthreads();   // compiler drains vmcnt before s_barrier -> LDS ready

    bf16x8 af[4], bfr[4];
#pragma unroll
    for (int m = 0; m < 4; m++)
      af[m] = *(const bf16x8*)(As + (wm * 64 + m * 16 + fr) * 32 + kk);
#pragma unroll
    for (int n = 0; n < 4; n++)
      bfr[n] = *(const bf16x8*)(Bs + (wn * 64 + n * 16 + fr) * 32 + kk);

#pragma unroll
    for (int m = 0; m < 4; m++)
#pragma unroll
      for (int n = 0; n < 4; n++)
        acc[m][n] = __builtin_amdgcn_mfma_f32_16x16x32_bf16(af[m], bfr[n], acc[m][n], 0, 0, 0);

    __syncthreads();   // protect LDS from next-iter restage
  }

  // epilogue: C/D layout col = lane&15, row = (lane>>4)*4 + j   [m89 verified]
#pragma unroll
  for (int m = 0; m < 4; m++) {
#pragma unroll
    for (int n = 0; n < 4; n++) {
      const int col  = n0 + wn * 64 + n * 16 + (lane & 15);
      const int rowb = m0 + wm * 64 + m * 16 + (lane >> 4) * 4;
      if (EPI == 0) {
        const float bv = bias[col];
#pragma unroll
        for (int j = 0; j < 4; j++) {
          C[(size_t)(rowb + j) * N + col] = acc[m][n][j] + bv;
        }
      } else {
#pragma unroll
        for (int j = 0; j < 4; j++) {
          const int row  = rowb + j;
          const int idxv = indices[row * 512 + (col >> 3)];
          const float cv = centroids[idxv * 8 + (col & 7)];
          const float w  = cv * wscale[row] + wbias[row] + acc[m][n][j];
          Cb[(size_t)row * N + col] = __float2bfloat16(w);
        }
      }
    }
  }
}

extern "C" void kernel_launch(void* const* d_in, const int* in_sizes, int n_in,
                              void* d_out, int out_size, void* d_ws, size_t ws_size,
                              hipStream_t stream)
{
  const float* x         = (const float*)d_in[0];   // [8192,4096]
  const float* centroids = (const float*)d_in[1];   // [4096,8]
  const int*   indices   = (const int*)d_in[2];     // [4096,512]
  const float* U         = (const float*)d_in[3];   // [4096,128]
  const float* S         = (const float*)d_in[4];   // [128]
  const float* Vt        = (const float*)d_in[5];   // [128,4096]
  const float* wscale    = (const float*)d_in[6];   // [4096]
  const float* wbias     = (const float*)d_in[7];   // [4096]
  const float* bias      = (const float*)d_in[8];   // [4096]
  float* out = (float*)d_out;                       // [8192,4096] f32

  char* ws = (char*)d_ws;
  bf16* xb   = (bf16*)(ws);                          // 8192*4096*2 = 64 MB
  bf16* Wb   = (bf16*)(ws + 67108864);               // 4096*4096*2 = 32 MB
  bf16* Ub   = (bf16*)(ws + 100663296);              // 4096*128*2  =  1 MB
  bf16* SVtT = (bf16*)(ws + 101711872);              // 4096*128*2  =  1 MB

  convert_x_kernel<<<2048, 256, 0, stream>>>(x, xb, 8192 * 4096);
  prep_kernel<<<2048, 256, 0, stream>>>(U, S, Vt, Ub, SVtT);

  // W[o][i] = codebook(o,i)*wscale[o] + wbias[o] + sum_r Ub[o][r]*SVtT[i][r]
  dim3 gW(4096 / 128, 4096 / 128);
  gemm_bt<1><<<gW, 256, 0, stream>>>(Ub, SVtT, nullptr, Wb, 4096, 4096, 128,
                                     nullptr, indices, centroids, wscale, wbias);

  // out[t][o] = sum_i xb[t][i]*Wb[o][i] + bias[o]
  dim3 gM(4096 / 128, 8192 / 128);
  gemm_bt<0><<<gM, 256, 0, stream>>>(xb, Wb, out, nullptr, 8192, 4096, 4096,
                                     bias, nullptr, nullptr, nullptr, nullptr);
}

// Round 2
// 333.095 us; speedup vs baseline: 1.1033x; 1.1033x over previous
//
#include <hip/hip_runtime.h>
#include <hip/hip_bf16.h>
#include <stdint.h>

using bf16 = __hip_bfloat16;
typedef __bf16 bf16x8 __attribute__((ext_vector_type(8)));
typedef float f32x4 __attribute__((ext_vector_type(4)));
typedef short short8 __attribute__((ext_vector_type(8)));

#define GLD_LDS16(gp, lp)                                                            \
  __builtin_amdgcn_global_load_lds(                                                  \
      (const __attribute__((address_space(1))) unsigned int*)(gp),                   \
      (__attribute__((address_space(3))) unsigned int*)(lp), 16, 0, 0)

// ---------------- x (f32) -> bf16 ----------------
__global__ __launch_bounds__(256) void convert_x_kernel(const float* __restrict__ x,
                                                        bf16* __restrict__ xb, int n)
{
  for (int i = (blockIdx.x * 256 + threadIdx.x) * 8; i < n; i += gridDim.x * 256 * 8) {
    float4 a = *(const float4*)(x + i);
    float4 b = *(const float4*)(x + i + 4);
    union { bf16 h[8]; short8 v; } u;
    u.h[0] = __float2bfloat16(a.x);
    u.h[1] = __float2bfloat16(a.y);
    u.h[2] = __float2bfloat16(a.z);
    u.h[3] = __float2bfloat16(a.w);
    u.h[4] = __float2bfloat16(b.x);
    u.h[5] = __float2bfloat16(b.y);
    u.h[6] = __float2bfloat16(b.z);
    u.h[7] = __float2bfloat16(b.w);
    *(short8*)(xb + i) = u.v;
  }
}

// ---------------- U -> bf16, SVtT[i][r] = S[r]*Vt[r][i] (bf16) ----------------
__global__ __launch_bounds__(256) void prep_kernel(const float* __restrict__ U,
                                                   const float* __restrict__ S,
                                                   const float* __restrict__ Vt,
                                                   bf16* __restrict__ Ub,
                                                   bf16* __restrict__ SVtT)
{
  int t = blockIdx.x * 256 + threadIdx.x;
  if (t < 4096 * 128) {
    Ub[t] = __float2bfloat16(U[t]);
    int i = t >> 7, r = t & 127;
    SVtT[t] = __float2bfloat16(S[r] * Vt[r * 4096 + i]);
  }
}

// ---------------- small 128x128 GEMM for W-build (K=128), round-0 structure ----------------
__global__ __launch_bounds__(256, 2) void gemm_wbuild(const bf16* __restrict__ A,
                                                      const bf16* __restrict__ B,
                                                      bf16* __restrict__ Cb,
                                                      int M, int N, int K,
                                                      const int* __restrict__ indices,
                                                      const float* __restrict__ centroids,
                                                      const float* __restrict__ wscale,
                                                      const float* __restrict__ wbias)
{
  __shared__ bf16 As[128 * 32];
  __shared__ bf16 Bs[128 * 32];

  const int tid  = threadIdx.x;
  const int m0   = blockIdx.y * 128;
  const int n0   = blockIdx.x * 128;
  const int wid  = tid >> 6;
  const int lane = tid & 63;
  const int wm   = wid >> 1;
  const int wn   = wid & 1;

  f32x4 acc[4][4] = {};

  const int sr = tid >> 2;
  const int sc = (tid & 3) * 8;
  const bf16* ga = A + (size_t)(m0 + sr) * K + sc;
  const bf16* gb = B + (size_t)(n0 + sr) * K + sc;
  bf16* la = &As[tid * 8];
  bf16* lb = &Bs[tid * 8];
  const size_t rowHop = (size_t)64 * K;

  const int kk = (lane >> 4) * 8;
  const int fr = lane & 15;

  for (int kt = 0; kt < K; kt += 32) {
    GLD_LDS16(ga + kt,          la);
    GLD_LDS16(ga + kt + rowHop, la + 2048);
    GLD_LDS16(gb + kt,          lb);
    GLD_LDS16(gb + kt + rowHop, lb + 2048);
    __syncthreads();

    bf16x8 af[4], bfr[4];
#pragma unroll
    for (int m = 0; m < 4; m++)
      af[m] = *(const bf16x8*)(As + (wm * 64 + m * 16 + fr) * 32 + kk);
#pragma unroll
    for (int n = 0; n < 4; n++)
      bfr[n] = *(const bf16x8*)(Bs + (wn * 64 + n * 16 + fr) * 32 + kk);

#pragma unroll
    for (int m = 0; m < 4; m++)
#pragma unroll
      for (int n = 0; n < 4; n++)
        acc[m][n] = __builtin_amdgcn_mfma_f32_16x16x32_bf16(af[m], bfr[n], acc[m][n], 0, 0, 0);

    __syncthreads();
  }

#pragma unroll
  for (int m = 0; m < 4; m++) {
#pragma unroll
    for (int n = 0; n < 4; n++) {
      const int col  = n0 + wn * 64 + n * 16 + (lane & 15);
      const int rowb = m0 + wm * 64 + m * 16 + (lane >> 4) * 4;
#pragma unroll
      for (int j = 0; j < 4; j++) {
        const int row  = rowb + j;
        const int idxv = indices[row * 512 + (col >> 3)];
        const float cv = centroids[idxv * 8 + (col & 7)];
        const float w  = cv * wscale[row] + wbias[row] + acc[m][n][j];
        Cb[(size_t)row * N + col] = __float2bfloat16(w);
      }
    }
  }
}

// ---------------- main 256x256 8-phase GEMM: C[m][n] = sum_k A[m,k]*B[n,k] + bias[n] ----------------
// 8 waves (2M x 4N), BK=64, double-buffered 128 KiB LDS, row-XOR swizzle
// ((row&7)<<4 on byte addr), counted vmcnt(8), setprio around MFMA clusters.
__global__ __launch_bounds__(512, 2) void gemm256(const bf16* __restrict__ A,
                                                  const bf16* __restrict__ B,
                                                  float* __restrict__ C,
                                                  const float* __restrict__ bias)
{
  extern __shared__ char smem[];     // [2][A 32KB | B 32KB] = 128 KiB
  constexpr int K  = 4096;
  constexpr int N  = 4096;
  constexpr int NT = 64;             // K / 64

  const int tid  = threadIdx.x;
  const int lane = tid & 63;
  const int wave = tid >> 6;
  const int wm   = wave >> 2;        // 0..1
  const int wn   = wave & 3;         // 0..3
  const int fr   = lane & 15;
  const int kk   = (lane >> 4) * 8;
  const int swx  = (fr & 7) << 4;    // read-side swizzle (row&7 == fr&7 for frag rows)

  // XCD-aware bijective swizzle: 512 blocks, 8 XCDs, 64 per XCD; grid 16(n) x 32(m)
  const int bid = blockIdx.x;
  const int swz = (bid & 7) * 64 + (bid >> 3);
  const int n0  = (swz & 15) * 256;
  const int m0  = (swz >> 4) * 256;

  // stage slots: inverse-swizzled global sources for linear global_load_lds dests.
  // A slots (idx qm*2+is): phys bytes qm*8192 + is*16384 + tid*16
  // B slots (idx qn*2+is): phys bytes qn*4096 + is*16384 + (tid>>8)*8192 + (tid&255)*16
  const bf16* gA[4]; const bf16* gB[4];
  int lA[4], lB[4];
#pragma unroll
  for (int q = 0; q < 2; q++)
#pragma unroll
    for (int is = 0; is < 2; is++) {
      const int p  = q * 8192 + is * 16384 + tid * 16;
      const int r  = p >> 7;
      const int kx = ((p ^ ((r & 7) << 4)) & 127) >> 1;
      gA[q * 2 + is] = A + (size_t)(m0 + r) * K + kx;
      lA[q * 2 + is] = p;
      const int pb  = q * 4096 + is * 16384 + (tid >> 8) * 8192 + (tid & 255) * 16;
      const int rb  = pb >> 7;
      const int kxb = ((pb ^ ((rb & 7) << 4)) & 127) >> 1;
      gB[q * 2 + is] = B + (size_t)(n0 + rb) * K + kxb;
      lB[q * 2 + is] = pb;
    }

  f32x4 acc[8][4] = {};

#define STAGE_A(s, bo, kt) GLD_LDS16(gA[s] + (kt), smem + (bo) + lA[s])
#define STAGE_B(s, bo, kt) GLD_LDS16(gB[s] + (kt), smem + (bo) + 32768 + lB[s])
#define VM8 asm volatile("s_waitcnt vmcnt(8)" ::: "memory")

#define PHASE(qm, qn, STAGES, WAITC)                                               \
  {                                                                                \
    bf16x8 aF[4][2], bF[2][2];                                                     \
    _Pragma("unroll") for (int mm = 0; mm < 4; mm++)                               \
      _Pragma("unroll") for (int ks = 0; ks < 2; ks++)                             \
        aF[mm][ks] = *(const bf16x8*)(smem + ab +                                  \
            ((((wm * 128 + (qm) * 64 + mm * 16 + fr) * 128) +                      \
              (ks * 32 + kk) * 2) ^ swx));                                         \
    _Pragma("unroll") for (int nn = 0; nn < 2; nn++)                               \
      _Pragma("unroll") for (int ks = 0; ks < 2; ks++)                             \
        bF[nn][ks] = *(const bf16x8*)(smem + ab + 32768 +                          \
            ((((wn * 64 + (qn) * 32 + nn * 16 + fr) * 128) +                       \
              (ks * 32 + kk) * 2) ^ swx));                                         \
    STAGES;                                                                        \
    WAITC;                                                                         \
    __builtin_amdgcn_s_barrier();                                                  \
    asm volatile("s_waitcnt lgkmcnt(0)" ::: "memory");                             \
    __builtin_amdgcn_sched_barrier(0);                                             \
    __builtin_amdgcn_s_setprio(1);                                                 \
    _Pragma("unroll") for (int mm = 0; mm < 4; mm++)                               \
      _Pragma("unroll") for (int nn = 0; nn < 2; nn++)                             \
        _Pragma("unroll") for (int ks = 0; ks < 2; ks++)                           \
          acc[(qm) * 4 + mm][(qn) * 2 + nn] =                                      \
              __builtin_amdgcn_mfma_f32_16x16x32_bf16(                             \
                  aF[mm][ks], bF[nn][ks], acc[(qm) * 4 + mm][(qn) * 2 + nn],       \
                  0, 0, 0);                                                        \
    __builtin_amdgcn_s_setprio(0);                                                 \
    __builtin_amdgcn_s_barrier();                                                  \
    __builtin_amdgcn_sched_barrier(0);                                             \
  }

  // prologue: tile0 full (A0,B0,A1,B1) + tile1 (A0,B0) = 12 loads, in this order
  STAGE_A(0, 0, 0); STAGE_A(1, 0, 0);
  STAGE_B(0, 0, 0); STAGE_B(1, 0, 0);
  STAGE_A(2, 0, 0); STAGE_A(3, 0, 0);
  STAGE_B(2, 0, 0); STAGE_B(3, 0, 0);
  STAGE_A(0, 65536, 64); STAGE_A(1, 65536, 64);
  STAGE_B(0, 65536, 64); STAGE_B(1, 65536, 64);
  VM8;
  __builtin_amdgcn_s_barrier();
  __builtin_amdgcn_sched_barrier(0);

  for (int t = 0; t < NT; t++) {
    const int ab  = (t & 1) * 65536;          // this tile's buffer
    const int nb  = 65536 - ab;               // next tile's buffer
    const int kt1 = ((t + 1) & (NT - 1)) * 64;  // wrap: tail stages land unread
    const int kt2 = ((t + 2) & (NT - 1)) * 64;

    // p0 (qm0,qn0): stage A1,B1 of t+1 -> other buf; wait ensures ...t-1.p0 landed
    PHASE(0, 0,
          { STAGE_A(2, nb, kt1); STAGE_A(3, nb, kt1);
            STAGE_B(2, nb, kt1); STAGE_B(3, nb, kt1); },
          VM8);
    // p1 (qm0,qn1): last reader of A0 region
    PHASE(0, 1, {}, (void)0);
    // p2 (qm1,qn0): A0 region free -> stage A0 of t+2 into this buf; last reader of B0
    PHASE(1, 0, { STAGE_A(0, ab, kt2); STAGE_A(1, ab, kt2); }, (void)0);
    // p3 (qm1,qn1): B0 free -> stage B0 of t+2; wait ensures ...t-1.p3 landed for next p0
    PHASE(1, 1, { STAGE_B(0, ab, kt2); STAGE_B(1, ab, kt2); }, VM8);
  }

  // epilogue: C/D layout col = lane&15, row = (lane>>4)*4 + j
#pragma unroll
  for (int mf = 0; mf < 8; mf++) {
#pragma unroll
    for (int nf = 0; nf < 4; nf++) {
      const int col  = n0 + wn * 64 + nf * 16 + fr;
      const int row0 = m0 + wm * 128 + mf * 16 + (lane >> 4) * 4;
      const float bv = bias[col];
#pragma unroll
      for (int j = 0; j < 4; j++)
        C[(size_t)(row0 + j) * N + col] = acc[mf][nf][j] + bv;
    }
  }
#undef PHASE
#undef VM8
#undef STAGE_A
#undef STAGE_B
}

extern "C" void kernel_launch(void* const* d_in, const int* in_sizes, int n_in,
                              void* d_out, int out_size, void* d_ws, size_t ws_size,
                              hipStream_t stream)
{
  const float* x         = (const float*)d_in[0];
  const float* centroids = (const float*)d_in[1];
  const int*   indices   = (const int*)d_in[2];
  const float* U         = (const float*)d_in[3];
  const float* S         = (const float*)d_in[4];
  const float* Vt        = (const float*)d_in[5];
  const float* wscale    = (const float*)d_in[6];
  const float* wbias     = (const float*)d_in[7];
  const float* bias      = (const float*)d_in[8];
  float* out = (float*)d_out;

  char* ws = (char*)d_ws;
  bf16* xb   = (bf16*)(ws);                          // 64 MB
  bf16* Wb   = (bf16*)(ws + 67108864);               // 32 MB
  bf16* Ub   = (bf16*)(ws + 100663296);              // 1 MB
  bf16* SVtT = (bf16*)(ws + 101711872);              // 1 MB

  convert_x_kernel<<<2048, 256, 0, stream>>>(x, xb, 8192 * 4096);
  prep_kernel<<<2048, 256, 0, stream>>>(U, S, Vt, Ub, SVtT);

  // W[o][i] = codebook(o,i)*wscale[o] + wbias[o] + sum_r Ub[o][r]*SVtT[i][r]
  dim3 gW(4096 / 128, 4096 / 128);
  gemm_wbuild<<<gW, 256, 0, stream>>>(Ub, SVtT, Wb, 4096, 4096, 128,
                                      indices, centroids, wscale, wbias);

  // out[t][o] = sum_i xb[t][i]*Wb[o][i] + bias[o]; grid 512 = 16(n) x 32(m)
  gemm256<<<512, 512, 131072, stream>>>(xb, Wb, out, bias);
}

// Round 3
// 304.870 us; speedup vs baseline: 1.2055x; 1.0926x over previous
//
#include <hip/hip_runtime.h>
#include <hip/hip_bf16.h>
#include <stdint.h>

using bf16 = __hip_bfloat16;
typedef __bf16 bf16x8 __attribute__((ext_vector_type(8)));
typedef float f32x4 __attribute__((ext_vector_type(4)));
typedef short short8 __attribute__((ext_vector_type(8)));

#define GLD_LDS16(gp, lp)                                                            \
  __builtin_amdgcn_global_load_lds(                                                  \
      (const __attribute__((address_space(1))) unsigned int*)(gp),                   \
      (__attribute__((address_space(3))) unsigned int*)(lp), 16, 0, 0)

// ---------------- x (f32) -> bf16 ----------------
__global__ __launch_bounds__(256) void convert_x_kernel(const float* __restrict__ x,
                                                        bf16* __restrict__ xb, int n)
{
  for (int i = (blockIdx.x * 256 + threadIdx.x) * 8; i < n; i += gridDim.x * 256 * 8) {
    float4 a = *(const float4*)(x + i);
    float4 b = *(const float4*)(x + i + 4);
    union { bf16 h[8]; short8 v; } u;
    u.h[0] = __float2bfloat16(a.x);
    u.h[1] = __float2bfloat16(a.y);
    u.h[2] = __float2bfloat16(a.z);
    u.h[3] = __float2bfloat16(a.w);
    u.h[4] = __float2bfloat16(b.x);
    u.h[5] = __float2bfloat16(b.y);
    u.h[6] = __float2bfloat16(b.z);
    u.h[7] = __float2bfloat16(b.w);
    *(short8*)(xb + i) = u.v;
  }
}

// ---------------- U -> bf16, SVtT[i][r] = S[r]*Vt[r][i] (bf16) ----------------
__global__ __launch_bounds__(256) void prep_kernel(const float* __restrict__ U,
                                                   const float* __restrict__ S,
                                                   const float* __restrict__ Vt,
                                                   bf16* __restrict__ Ub,
                                                   bf16* __restrict__ SVtT)
{
  int t = blockIdx.x * 256 + threadIdx.x;
  if (t < 4096 * 128) {
    Ub[t] = __float2bfloat16(U[t]);
    int i = t >> 7, r = t & 127;
    SVtT[t] = __float2bfloat16(S[r] * Vt[r * 4096 + i]);
  }
}

// ---------------- small 128x128 GEMM for W-build (K=128) ----------------
__global__ __launch_bounds__(256, 2) void gemm_wbuild(const bf16* __restrict__ A,
                                                      const bf16* __restrict__ B,
                                                      bf16* __restrict__ Cb,
                                                      int M, int N, int K,
                                                      const int* __restrict__ indices,
                                                      const float* __restrict__ centroids,
                                                      const float* __restrict__ wscale,
                                                      const float* __restrict__ wbias)
{
  __shared__ bf16 As[128 * 32];
  __shared__ bf16 Bs[128 * 32];

  const int tid  = threadIdx.x;
  const int m0   = blockIdx.y * 128;
  const int n0   = blockIdx.x * 128;
  const int wid  = tid >> 6;
  const int lane = tid & 63;
  const int wm   = wid >> 1;
  const int wn   = wid & 1;

  f32x4 acc[4][4] = {};

  const int sr = tid >> 2;
  const int sc = (tid & 3) * 8;
  const bf16* ga = A + (size_t)(m0 + sr) * K + sc;
  const bf16* gb = B + (size_t)(n0 + sr) * K + sc;
  bf16* la = &As[tid * 8];
  bf16* lb = &Bs[tid * 8];
  const size_t rowHop = (size_t)64 * K;

  const int kk = (lane >> 4) * 8;
  const int fr = lane & 15;

  for (int kt = 0; kt < K; kt += 32) {
    GLD_LDS16(ga + kt,          la);
    GLD_LDS16(ga + kt + rowHop, la + 2048);
    GLD_LDS16(gb + kt,          lb);
    GLD_LDS16(gb + kt + rowHop, lb + 2048);
    __syncthreads();

    bf16x8 af[4], bfr[4];
#pragma unroll
    for (int m = 0; m < 4; m++)
      af[m] = *(const bf16x8*)(As + (wm * 64 + m * 16 + fr) * 32 + kk);
#pragma unroll
    for (int n = 0; n < 4; n++)
      bfr[n] = *(const bf16x8*)(Bs + (wn * 64 + n * 16 + fr) * 32 + kk);

#pragma unroll
    for (int m = 0; m < 4; m++)
#pragma unroll
      for (int n = 0; n < 4; n++)
        acc[m][n] = __builtin_amdgcn_mfma_f32_16x16x32_bf16(af[m], bfr[n], acc[m][n], 0, 0, 0);

    __syncthreads();
  }

#pragma unroll
  for (int m = 0; m < 4; m++) {
#pragma unroll
    for (int n = 0; n < 4; n++) {
      const int col  = n0 + wn * 64 + n * 16 + (lane & 15);
      const int rowb = m0 + wm * 64 + m * 16 + (lane >> 4) * 4;
#pragma unroll
      for (int j = 0; j < 4; j++) {
        const int row  = rowb + j;
        const int idxv = indices[row * 512 + (col >> 3)];
        const float cv = centroids[idxv * 8 + (col & 7)];
        const float w  = cv * wscale[row] + wbias[row] + acc[m][n][j];
        Cb[(size_t)row * N + col] = __float2bfloat16(w);
      }
    }
  }
}

// ---------------- main 256x256 snake-order 4-phase GEMM ----------------
// 8 waves (2M x 4N), BK=64, dbuf 128 KiB LDS, row-XOR swizzle, fragment reuse:
// p0(qm0,qn0): load aF+bF0      p1(qm0,qn1): load bF1
// p2(qm1,qn1): load aF          p3(qm1,qn0): reload bF0
// 28 ds_read_b128/wave/tile (was 48). Counted vmcnt(6) once per tile.
__global__ __launch_bounds__(512, 2) void gemm256(const bf16* __restrict__ A,
                                                  const bf16* __restrict__ B,
                                                  float* __restrict__ C,
                                                  const float* __restrict__ bias)
{
  extern __shared__ char smem[];     // [2][A 32KB | B 32KB] = 128 KiB
  constexpr int K  = 4096;
  constexpr int N  = 4096;
  constexpr int NT = 64;             // K / 64

  const int tid  = threadIdx.x;
  const int lane = tid & 63;
  const int wave = tid >> 6;
  const int wm   = wave >> 2;        // 0..1
  const int wn   = wave & 3;         // 0..3
  const int fr   = lane & 15;
  const int kk   = (lane >> 4) * 8;
  const int swx  = (fr & 7) << 4;    // read-side swizzle

  // XCD-aware swizzle, 8x8 group per XCD: grid m=32, n=16
  const int bid = blockIdx.x;
  const int xcd = bid & 7;
  const int idx = bid >> 3;          // 0..63
  const int mi  = (xcd & 3) * 8 + (idx & 7);
  const int ni  = (xcd >> 2) * 8 + (idx >> 3);
  const int m0  = mi * 256;
  const int n0  = ni * 256;

  // stage slots: inverse-swizzled global sources for linear global_load_lds dests.
  const bf16* gA[4]; const bf16* gB[4];
  int lA[4], lB[4];
#pragma unroll
  for (int q = 0; q < 2; q++)
#pragma unroll
    for (int is = 0; is < 2; is++) {
      const int p  = q * 8192 + is * 16384 + tid * 16;
      const int r  = p >> 7;
      const int kx = ((p ^ ((r & 7) << 4)) & 127) >> 1;
      gA[q * 2 + is] = A + (size_t)(m0 + r) * K + kx;
      lA[q * 2 + is] = p;
      const int pb  = q * 4096 + is * 16384 + (tid >> 8) * 8192 + (tid & 255) * 16;
      const int rb  = pb >> 7;
      const int kxb = ((pb ^ ((rb & 7) << 4)) & 127) >> 1;
      gB[q * 2 + is] = B + (size_t)(n0 + rb) * K + kxb;
      lB[q * 2 + is] = pb;
    }

  f32x4 acc[8][4] = {};

#define STAGE_A(s, bo, kt) GLD_LDS16(gA[s] + (kt), smem + (bo) + lA[s])
#define STAGE_B(s, bo, kt) GLD_LDS16(gB[s] + (kt), smem + (bo) + 32768 + lB[s])

#define LOAD_AF(qm)                                                                \
  _Pragma("unroll") for (int mm = 0; mm < 4; mm++)                                 \
    _Pragma("unroll") for (int ks = 0; ks < 2; ks++)                               \
      aF[mm][ks] = *(const bf16x8*)(smem + ab +                                    \
          ((((wm * 128 + (qm) * 64 + mm * 16 + fr) * 128) +                        \
            (ks * 32 + kk) * 2) ^ swx));

#define LOAD_BF(dst, qn)                                                           \
  _Pragma("unroll") for (int nn = 0; nn < 2; nn++)                                 \
    _Pragma("unroll") for (int ks = 0; ks < 2; ks++)                               \
      dst[nn][ks] = *(const bf16x8*)(smem + ab + 32768 +                           \
          ((((wn * 64 + (qn) * 32 + nn * 16 + fr) * 128) +                         \
            (ks * 32 + kk) * 2) ^ swx));

#define PHASE_TAIL(qm, qn, bfv)                                                    \
  __builtin_amdgcn_s_barrier();                                                    \
  asm volatile("s_waitcnt lgkmcnt(0)" ::: "memory");                               \
  __builtin_amdgcn_sched_barrier(0);                                               \
  __builtin_amdgcn_s_setprio(1);                                                   \
  _Pragma("unroll") for (int mm = 0; mm < 4; mm++)                                 \
    _Pragma("unroll") for (int nn = 0; nn < 2; nn++)                               \
      _Pragma("unroll") for (int ks = 0; ks < 2; ks++)                             \
        acc[(qm) * 4 + mm][(qn) * 2 + nn] =                                        \
            __builtin_amdgcn_mfma_f32_16x16x32_bf16(                               \
                aF[mm][ks], bfv[nn][ks], acc[(qm) * 4 + mm][(qn) * 2 + nn],        \
                0, 0, 0);                                                          \
  __builtin_amdgcn_s_setprio(0);                                                   \
  __builtin_amdgcn_s_barrier();                                                    \
  __builtin_amdgcn_sched_barrier(0);

  // prologue: tile0 all 8 slots -> buf0; tile1 slots A0A1,B2B3,A2A3 -> buf1
  STAGE_A(0, 0, 0); STAGE_A(1, 0, 0);
  STAGE_B(2, 0, 0); STAGE_B(3, 0, 0);
  STAGE_A(2, 0, 0); STAGE_A(3, 0, 0);
  STAGE_B(0, 0, 0); STAGE_B(1, 0, 0);
  STAGE_A(0, 65536, 64); STAGE_A(1, 65536, 64);
  STAGE_B(2, 65536, 64); STAGE_B(3, 65536, 64);
  STAGE_A(2, 65536, 64); STAGE_A(3, 65536, 64);
  asm volatile("s_waitcnt vmcnt(6)" ::: "memory");
  __builtin_amdgcn_s_barrier();
  __builtin_amdgcn_sched_barrier(0);

  for (int t = 0; t < NT; t++) {
    const int ab  = (t & 1) * 65536;            // this tile's buffer
    const int nb  = 65536 - ab;                 // next tile's buffer
    const int kt1 = ((t + 1) & (NT - 1)) * 64;
    const int kt2 = ((t + 2) & (NT - 1)) * 64;

    bf16x8 aF[4][2], bF0[2][2], bF1[2][2];

    // p0 (qm0,qn0): load aF(qm0) + bF0; stage B0B1 of t+1 -> nb
    LOAD_AF(0); LOAD_BF(bF0, 0);
    STAGE_B(0, nb, kt1); STAGE_B(1, nb, kt1);
    PHASE_TAIL(0, 0, bF0);

    // p1 (qm0,qn1): load bF1, reuse aF; A-qm0 region free -> stage A0A1 of t+2
    LOAD_BF(bF1, 1);
    STAGE_A(0, ab, kt2); STAGE_A(1, ab, kt2);
    PHASE_TAIL(0, 1, bF1);

    // p2 (qm1,qn1): load aF(qm1), reuse bF1; B-qn1 free -> stage B2B3 of t+2
    LOAD_AF(1);
    STAGE_B(2, ab, kt2); STAGE_B(3, ab, kt2);
    PHASE_TAIL(1, 1, bF1);

    // p3 (qm1,qn0): reload bF0; A-qm1 free -> stage A2A3 of t+2; counted wait
    LOAD_BF(bF0, 0);
    STAGE_A(2, ab, kt2); STAGE_A(3, ab, kt2);
    asm volatile("s_waitcnt vmcnt(6)" ::: "memory");
    PHASE_TAIL(1, 0, bF0);
  }

  // epilogue: C/D layout col = lane&15, row = (lane>>4)*4 + j
#pragma unroll
  for (int mf = 0; mf < 8; mf++) {
#pragma unroll
    for (int nf = 0; nf < 4; nf++) {
      const int col  = n0 + wn * 64 + nf * 16 + fr;
      const int row0 = m0 + wm * 128 + mf * 16 + (lane >> 4) * 4;
      const float bv = bias[col];
#pragma unroll
      for (int j = 0; j < 4; j++)
        C[(size_t)(row0 + j) * N + col] = acc[mf][nf][j] + bv;
    }
  }
#undef PHASE_TAIL
#undef LOAD_AF
#undef LOAD_BF
#undef STAGE_A
#undef STAGE_B
}

extern "C" void kernel_launch(void* const* d_in, const int* in_sizes, int n_in,
                              void* d_out, int out_size, void* d_ws, size_t ws_size,
                              hipStream_t stream)
{
  const float* x         = (const float*)d_in[0];
  const float* centroids = (const float*)d_in[1];
  const int*   indices   = (const int*)d_in[2];
  const float* U         = (const float*)d_in[3];
  const float* S         = (const float*)d_in[4];
  const float* Vt        = (const float*)d_in[5];
  const float* wscale    = (const float*)d_in[6];
  const float* wbias     = (const float*)d_in[7];
  const float* bias      = (const float*)d_in[8];
  float* out = (float*)d_out;

  char* ws = (char*)d_ws;
  bf16* xb   = (bf16*)(ws);                          // 64 MB
  bf16* Wb   = (bf16*)(ws + 67108864);               // 32 MB
  bf16* Ub   = (bf16*)(ws + 100663296);              // 1 MB
  bf16* SVtT = (bf16*)(ws + 101711872);              // 1 MB

  convert_x_kernel<<<2048, 256, 0, stream>>>(x, xb, 8192 * 4096);
  prep_kernel<<<2048, 256, 0, stream>>>(U, S, Vt, Ub, SVtT);

  // W[o][i] = codebook(o,i)*wscale[o] + wbias[o] + sum_r Ub[o][r]*SVtT[i][r]
  dim3 gW(4096 / 128, 4096 / 128);
  gemm_wbuild<<<gW, 256, 0, stream>>>(Ub, SVtT, Wb, 4096, 4096, 128,
                                      indices, centroids, wscale, wbias);

  // out[t][o] = sum_i xb[t][i]*Wb[o][i] + bias[o]
  gemm256<<<512, 512, 131072, stream>>>(xb, Wb, out, bias);
}

// Round 4
// 302.193 us; speedup vs baseline: 1.2162x; 1.0089x over previous
//
#include <hip/hip_runtime.h>
#include <hip/hip_bf16.h>
#include <stdint.h>

using bf16 = __hip_bfloat16;
typedef __bf16 bf16x8 __attribute__((ext_vector_type(8)));
typedef float f32x4 __attribute__((ext_vector_type(4)));
typedef short short8 __attribute__((ext_vector_type(8)));

#define GLD_LDS16(gp, lp)                                                            \
  __builtin_amdgcn_global_load_lds(                                                  \
      (const __attribute__((address_space(1))) unsigned int*)(gp),                   \
      (__attribute__((address_space(3))) unsigned int*)(lp), 16, 0, 0)

// ---------------- x (f32) -> bf16 ----------------
__global__ __launch_bounds__(256) void convert_x_kernel(const float* __restrict__ x,
                                                        bf16* __restrict__ xb, int n)
{
  for (int i = (blockIdx.x * 256 + threadIdx.x) * 8; i < n; i += gridDim.x * 256 * 8) {
    float4 a = *(const float4*)(x + i);
    float4 b = *(const float4*)(x + i + 4);
    union { bf16 h[8]; short8 v; } u;
    u.h[0] = __float2bfloat16(a.x);
    u.h[1] = __float2bfloat16(a.y);
    u.h[2] = __float2bfloat16(a.z);
    u.h[3] = __float2bfloat16(a.w);
    u.h[4] = __float2bfloat16(b.x);
    u.h[5] = __float2bfloat16(b.y);
    u.h[6] = __float2bfloat16(b.z);
    u.h[7] = __float2bfloat16(b.w);
    *(short8*)(xb + i) = u.v;
  }
}

// ---------------- U -> bf16, SVtT[i][r] = S[r]*Vt[r][i] (bf16) ----------------
__global__ __launch_bounds__(256) void prep_kernel(const float* __restrict__ U,
                                                   const float* __restrict__ S,
                                                   const float* __restrict__ Vt,
                                                   bf16* __restrict__ Ub,
                                                   bf16* __restrict__ SVtT)
{
  int t = blockIdx.x * 256 + threadIdx.x;
  if (t < 4096 * 128) {
    Ub[t] = __float2bfloat16(U[t]);
    int i = t >> 7, r = t & 127;
    SVtT[t] = __float2bfloat16(S[r] * Vt[r * 4096 + i]);
  }
}

// ---------------- small 128x128 GEMM for W-build (K=128) ----------------
__global__ __launch_bounds__(256, 2) void gemm_wbuild(const bf16* __restrict__ A,
                                                      const bf16* __restrict__ B,
                                                      bf16* __restrict__ Cb,
                                                      int M, int N, int K,
                                                      const int* __restrict__ indices,
                                                      const float* __restrict__ centroids,
                                                      const float* __restrict__ wscale,
                                                      const float* __restrict__ wbias)
{
  __shared__ bf16 As[128 * 32];
  __shared__ bf16 Bs[128 * 32];

  const int tid  = threadIdx.x;
  const int m0   = blockIdx.y * 128;
  const int n0   = blockIdx.x * 128;
  const int wid  = tid >> 6;
  const int lane = tid & 63;
  const int wm   = wid >> 1;
  const int wn   = wid & 1;

  f32x4 acc[4][4] = {};

  const int sr = tid >> 2;
  const int sc = (tid & 3) * 8;
  const bf16* ga = A + (size_t)(m0 + sr) * K + sc;
  const bf16* gb = B + (size_t)(n0 + sr) * K + sc;
  bf16* la = &As[tid * 8];
  bf16* lb = &Bs[tid * 8];
  const size_t rowHop = (size_t)64 * K;

  const int kk = (lane >> 4) * 8;
  const int fr = lane & 15;

  for (int kt = 0; kt < K; kt += 32) {
    GLD_LDS16(ga + kt,          la);
    GLD_LDS16(ga + kt + rowHop, la + 2048);
    GLD_LDS16(gb + kt,          lb);
    GLD_LDS16(gb + kt + rowHop, lb + 2048);
    __syncthreads();

    bf16x8 af[4], bfr[4];
#pragma unroll
    for (int m = 0; m < 4; m++)
      af[m] = *(const bf16x8*)(As + (wm * 64 + m * 16 + fr) * 32 + kk);
#pragma unroll
    for (int n = 0; n < 4; n++)
      bfr[n] = *(const bf16x8*)(Bs + (wn * 64 + n * 16 + fr) * 32 + kk);

#pragma unroll
    for (int m = 0; m < 4; m++)
#pragma unroll
      for (int n = 0; n < 4; n++)
        acc[m][n] = __builtin_amdgcn_mfma_f32_16x16x32_bf16(af[m], bfr[n], acc[m][n], 0, 0, 0);

    __syncthreads();
  }

#pragma unroll
  for (int m = 0; m < 4; m++) {
#pragma unroll
    for (int n = 0; n < 4; n++) {
      const int col  = n0 + wn * 64 + n * 16 + (lane & 15);
      const int rowb = m0 + wm * 64 + m * 16 + (lane >> 4) * 4;
#pragma unroll
      for (int j = 0; j < 4; j++) {
        const int row  = rowb + j;
        const int idxv = indices[row * 512 + (col >> 3)];
        const float cv = centroids[idxv * 8 + (col & 7)];
        const float w  = cv * wscale[row] + wbias[row] + acc[m][n][j];
        Cb[(size_t)row * N + col] = __float2bfloat16(w);
      }
    }
  }
}

// ---------------- main 256x256 pipelined GEMM ----------------
// 8 waves (2M x 4N), BK=64, dbuf 128 KiB LDS, row-XOR swizzle.
// ONE barrier per phase; fragments ds_read one phase early so the compiler
// emits counted lgkmcnt before each MFMA cluster (reads overlap barriers/stages).
// Region schedule per tile t (ab = tile t's buffer, nb = other):
//   p0: stage B0B1(t+1)->nb | pre-load b1   | MFMA(aq0,b0)
//   p1: stage A0A1(t+2)->ab |               | MFMA(aq0,b1) | post-load aq1
//   p2: stage B2B3(t+2)->ab | pre-load b0r  | MFMA(aq1,b1)
//   p3: vmcnt(4) | stage A2A3(t+2)->ab |    | MFMA(aq1,b0r)| post-load aq0,b0 from nb
__global__ __launch_bounds__(512, 2) void gemm256(const bf16* __restrict__ A,
                                                  const bf16* __restrict__ B,
                                                  float* __restrict__ C,
                                                  const float* __restrict__ bias)
{
  extern __shared__ char smem[];     // [2][A 32KB | B 32KB] = 128 KiB
  constexpr int K  = 4096;
  constexpr int N  = 4096;
  constexpr int NT = 64;             // K / 64

  const int tid  = threadIdx.x;
  const int lane = tid & 63;
  const int wave = tid >> 6;
  const int wm   = wave >> 2;        // 0..1
  const int wn   = wave & 3;         // 0..3
  const int fr   = lane & 15;
  const int kk   = (lane >> 4) * 8;
  const int swx  = (fr & 7) << 4;    // read-side swizzle

  // XCD-aware swizzle, 8x8 tile group per XCD: grid m=32, n=16
  const int bid = blockIdx.x;
  const int xcd = bid & 7;
  const int idx = bid >> 3;
  const int mi  = (xcd & 3) * 8 + (idx & 7);
  const int ni  = (xcd >> 2) * 8 + (idx >> 3);
  const int m0  = mi * 256;
  const int n0  = ni * 256;

  // stage bases: inverse-swizzled global source for linear global_load_lds dest.
  const int pA = tid * 16;
  const int rA = pA >> 7;
  const int kA = ((pA ^ ((rA & 7) << 4)) & 127) >> 1;
  const bf16* gA0 = A + (size_t)(m0 + rA) * K + kA;
  const int pB = (tid >> 8) * 8192 + (tid & 255) * 16;
  const int rB = pB >> 7;
  const int kB = ((pB ^ ((rB & 7) << 4)) & 127) >> 1;
  const bf16* gB0 = B + (size_t)(n0 + rB) * K + kB;

  f32x4 acc[8][4] = {};

  // slot (rowdelta, lds-byte-delta): A: s0(0,0) s1(128,16384) s2(64,8192) s3(192,24576)
  //                                  B: s0(0,0) s1(128,16384) s2(32,4096) s3(160,20480)
#define STAGE_A0(bo, kt) GLD_LDS16(gA0 + (kt),              smem + (bo) + pA)
#define STAGE_A1(bo, kt) GLD_LDS16(gA0 + 128 * 4096 + (kt), smem + (bo) + pA + 16384)
#define STAGE_A2(bo, kt) GLD_LDS16(gA0 +  64 * 4096 + (kt), smem + (bo) + pA + 8192)
#define STAGE_A3(bo, kt) GLD_LDS16(gA0 + 192 * 4096 + (kt), smem + (bo) + pA + 24576)
#define STAGE_B0(bo, kt) GLD_LDS16(gB0 + (kt),              smem + (bo) + 32768 + pB)
#define STAGE_B1(bo, kt) GLD_LDS16(gB0 + 128 * 4096 + (kt), smem + (bo) + 32768 + pB + 16384)
#define STAGE_B2(bo, kt) GLD_LDS16(gB0 +  32 * 4096 + (kt), smem + (bo) + 32768 + pB + 4096)
#define STAGE_B3(bo, kt) GLD_LDS16(gB0 + 160 * 4096 + (kt), smem + (bo) + 32768 + pB + 20480)

#define LOAD_AQ(dst, qm, bo)                                                        \
  _Pragma("unroll") for (int mm = 0; mm < 4; mm++)                                  \
    _Pragma("unroll") for (int ks = 0; ks < 2; ks++)                                \
      dst[mm][ks] = *(const bf16x8*)(smem + (bo) +                                  \
          ((((wm * 128 + (qm) * 64 + mm * 16 + fr) * 128) +                         \
            (ks * 32 + kk) * 2) ^ swx));

#define LOAD_BQ(dst, qn, bo)                                                        \
  _Pragma("unroll") for (int nn = 0; nn < 2; nn++)                                  \
    _Pragma("unroll") for (int ks = 0; ks < 2; ks++)                                \
      dst[nn][ks] = *(const bf16x8*)(smem + (bo) + 32768 +                          \
          ((((wn * 64 + (qn) * 32 + nn * 16 + fr) * 128) +                          \
            (ks * 32 + kk) * 2) ^ swx));

  // ks-outer: 8 independent MFMAs between same-acc dependents
#define CLUSTER(qm, qn, av, bv)                                                     \
  __builtin_amdgcn_s_setprio(1);                                                    \
  _Pragma("unroll") for (int ks = 0; ks < 2; ks++)                                  \
    _Pragma("unroll") for (int mm = 0; mm < 4; mm++)                                \
      _Pragma("unroll") for (int nn = 0; nn < 2; nn++)                              \
        acc[(qm) * 4 + mm][(qn) * 2 + nn] =                                         \
            __builtin_amdgcn_mfma_f32_16x16x32_bf16(                                \
                av[mm][ks], bv[nn][ks], acc[(qm) * 4 + mm][(qn) * 2 + nn],          \
                0, 0, 0);                                                           \
  __builtin_amdgcn_s_setprio(0);

#define SBAR   __builtin_amdgcn_s_barrier()
#define SCHED0 __builtin_amdgcn_sched_barrier(0)

  bf16x8 aq0[4][2], aq1[4][2], b0[2][2], b1[2][2], b0r[2][2];

  // prologue: tile0 all 8 slots -> buf0 (A0A1,B0B1 first), tile1 A0A1/B2B3/A2A3 -> buf1
  STAGE_A0(0, 0); STAGE_A1(0, 0);
  STAGE_B0(0, 0); STAGE_B1(0, 0);
  STAGE_B2(0, 0); STAGE_B3(0, 0);
  STAGE_A2(0, 0); STAGE_A3(0, 0);
  STAGE_A0(65536, 64); STAGE_A1(65536, 64);
  STAGE_B2(65536, 64); STAGE_B3(65536, 64);
  STAGE_A2(65536, 64); STAGE_A3(65536, 64);
  asm volatile("s_waitcnt vmcnt(6)" ::: "memory");   // tile0's 8 slots landed
  SBAR;
  LOAD_AQ(aq0, 0, 0);
  LOAD_BQ(b0, 0, 0);
  SCHED0;

  for (int t = 0; t < NT; t++) {
    const int ab  = (t & 1) * 65536;
    const int nb  = 65536 - ab;
    const int kt1 = ((t + 1) & (NT - 1)) * 64;
    const int kt2 = ((t + 2) & (NT - 1)) * 64;

    // p0 (qm0,qn0)
    SBAR;
    STAGE_B0(nb, kt1); STAGE_B1(nb, kt1);
    LOAD_BQ(b1, 1, ab);
    SCHED0;
    CLUSTER(0, 0, aq0, b0);
    SCHED0;

    // p1 (qm0,qn1)
    SBAR;
    STAGE_A0(ab, kt2); STAGE_A1(ab, kt2);
    SCHED0;
    CLUSTER(0, 1, aq0, b1);
    SCHED0;
    LOAD_AQ(aq1, 1, ab);
    SCHED0;

    // p2 (qm1,qn1)
    SBAR;
    STAGE_B2(ab, kt2); STAGE_B3(ab, kt2);
    LOAD_BQ(b0r, 0, ab);
    SCHED0;
    CLUSTER(1, 1, aq1, b1);
    SCHED0;

    // p3 (qm1,qn0)
    asm volatile("s_waitcnt vmcnt(4)" ::: "memory");  // B0B1(t+1)@t.p0 + A0A1(t+1)@(t-1).p1 landed
    SBAR;
    STAGE_A2(ab, kt2); STAGE_A3(ab, kt2);
    SCHED0;
    CLUSTER(1, 0, aq1, b0r);
    SCHED0;
    LOAD_AQ(aq0, 0, nb);
    LOAD_BQ(b0, 0, nb);
    SCHED0;
  }

  // epilogue: C/D layout col = lane&15, row = (lane>>4)*4 + j
#pragma unroll
  for (int mf = 0; mf < 8; mf++) {
#pragma unroll
    for (int nf = 0; nf < 4; nf++) {
      const int col  = n0 + wn * 64 + nf * 16 + fr;
      const int row0 = m0 + wm * 128 + mf * 16 + (lane >> 4) * 4;
      const float bv = bias[col];
#pragma unroll
      for (int j = 0; j < 4; j++)
        C[(size_t)(row0 + j) * N + col] = acc[mf][nf][j] + bv;
    }
  }
#undef CLUSTER
#undef LOAD_AQ
#undef LOAD_BQ
#undef SBAR
#undef SCHED0
}

extern "C" void kernel_launch(void* const* d_in, const int* in_sizes, int n_in,
                              void* d_out, int out_size, void* d_ws, size_t ws_size,
                              hipStream_t stream)
{
  const float* x         = (const float*)d_in[0];
  const float* centroids = (const float*)d_in[1];
  const int*   indices   = (const int*)d_in[2];
  const float* U         = (const float*)d_in[3];
  const float* S         = (const float*)d_in[4];
  const float* Vt        = (const float*)d_in[5];
  const float* wscale    = (const float*)d_in[6];
  const float* wbias     = (const float*)d_in[7];
  const float* bias      = (const float*)d_in[8];
  float* out = (float*)d_out;

  char* ws = (char*)d_ws;
  bf16* xb   = (bf16*)(ws);                          // 64 MB
  bf16* Wb   = (bf16*)(ws + 67108864);               // 32 MB
  bf16* Ub   = (bf16*)(ws + 100663296);              // 1 MB
  bf16* SVtT = (bf16*)(ws + 101711872);              // 1 MB

  convert_x_kernel<<<2048, 256, 0, stream>>>(x, xb, 8192 * 4096);
  prep_kernel<<<2048, 256, 0, stream>>>(U, S, Vt, Ub, SVtT);

  // W[o][i] = codebook(o,i)*wscale[o] + wbias[o] + sum_r Ub[o][r]*SVtT[i][r]
  dim3 gW(4096 / 128, 4096 / 128);
  gemm_wbuild<<<gW, 256, 0, stream>>>(Ub, SVtT, Wb, 4096, 4096, 128,
                                      indices, centroids, wscale, wbias);

  // out[t][o] = sum_i xb[t][i]*Wb[o][i] + bias[o]
  gemm256<<<512, 512, 131072, stream>>>(xb, Wb, out, bias);
}

// Round 6
// 290.308 us; speedup vs baseline: 1.2660x; 1.0409x over previous
//
#include <hip/hip_runtime.h>
#include <hip/hip_bf16.h>
#include <stdint.h>

using bf16 = __hip_bfloat16;
typedef __bf16 bf16x8 __attribute__((ext_vector_type(8)));
typedef float f32x4 __attribute__((ext_vector_type(4)));
typedef short short8 __attribute__((ext_vector_type(8)));

#define GLD_LDS16(gp, lp)                                                            \
  __builtin_amdgcn_global_load_lds(                                                  \
      (const __attribute__((address_space(1))) unsigned int*)(gp),                   \
      (__attribute__((address_space(3))) unsigned int*)(lp), 16, 0, 0)

// ---------------- x (f32) -> bf16 ----------------
__global__ __launch_bounds__(256) void convert_x_kernel(const float* __restrict__ x,
                                                        bf16* __restrict__ xb, int n)
{
  for (int i = (blockIdx.x * 256 + threadIdx.x) * 8; i < n; i += gridDim.x * 256 * 8) {
    float4 a = *(const float4*)(x + i);
    float4 b = *(const float4*)(x + i + 4);
    union { bf16 h[8]; short8 v; } u;
    u.h[0] = __float2bfloat16(a.x);
    u.h[1] = __float2bfloat16(a.y);
    u.h[2] = __float2bfloat16(a.z);
    u.h[3] = __float2bfloat16(a.w);
    u.h[4] = __float2bfloat16(b.x);
    u.h[5] = __float2bfloat16(b.y);
    u.h[6] = __float2bfloat16(b.z);
    u.h[7] = __float2bfloat16(b.w);
    *(short8*)(xb + i) = u.v;
  }
}

// ---------------- U -> bf16, SVtT[i][r] = S[r]*Vt[r][i] (bf16) ----------------
__global__ __launch_bounds__(256) void prep_kernel(const float* __restrict__ U,
                                                   const float* __restrict__ S,
                                                   const float* __restrict__ Vt,
                                                   bf16* __restrict__ Ub,
                                                   bf16* __restrict__ SVtT)
{
  int t = blockIdx.x * 256 + threadIdx.x;
  if (t < 4096 * 128) {
    Ub[t] = __float2bfloat16(U[t]);
    int i = t >> 7, r = t & 127;
    SVtT[t] = __float2bfloat16(S[r] * Vt[r * 4096 + i]);
  }
}

// ---------------- small 128x128 GEMM for W-build (K=128) ----------------
__global__ __launch_bounds__(256, 2) void gemm_wbuild(const bf16* __restrict__ A,
                                                      const bf16* __restrict__ B,
                                                      bf16* __restrict__ Cb,
                                                      int M, int N, int K,
                                                      const int* __restrict__ indices,
                                                      const float* __restrict__ centroids,
                                                      const float* __restrict__ wscale,
                                                      const float* __restrict__ wbias)
{
  __shared__ bf16 As[128 * 32];
  __shared__ bf16 Bs[128 * 32];

  const int tid  = threadIdx.x;
  const int m0   = blockIdx.y * 128;
  const int n0   = blockIdx.x * 128;
  const int wid  = tid >> 6;
  const int lane = tid & 63;
  const int wm   = wid >> 1;
  const int wn   = wid & 1;

  f32x4 acc[4][4] = {};

  const int sr = tid >> 2;
  const int sc = (tid & 3) * 8;
  const bf16* ga = A + (size_t)(m0 + sr) * K + sc;
  const bf16* gb = B + (size_t)(n0 + sr) * K + sc;
  bf16* la = &As[tid * 8];
  bf16* lb = &Bs[tid * 8];
  const size_t rowHop = (size_t)64 * K;

  const int kk = (lane >> 4) * 8;
  const int fr = lane & 15;

  for (int kt = 0; kt < K; kt += 32) {
    GLD_LDS16(ga + kt,          la);
    GLD_LDS16(ga + kt + rowHop, la + 2048);
    GLD_LDS16(gb + kt,          lb);
    GLD_LDS16(gb + kt + rowHop, lb + 2048);
    __syncthreads();

    bf16x8 af[4], bfr[4];
#pragma unroll
    for (int m = 0; m < 4; m++)
      af[m] = *(const bf16x8*)(As + (wm * 64 + m * 16 + fr) * 32 + kk);
#pragma unroll
    for (int n = 0; n < 4; n++)
      bfr[n] = *(const bf16x8*)(Bs + (wn * 64 + n * 16 + fr) * 32 + kk);

#pragma unroll
    for (int m = 0; m < 4; m++)
#pragma unroll
      for (int n = 0; n < 4; n++)
        acc[m][n] = __builtin_amdgcn_mfma_f32_16x16x32_bf16(af[m], bfr[n], acc[m][n], 0, 0, 0);

    __syncthreads();
  }

#pragma unroll
  for (int m = 0; m < 4; m++) {
#pragma unroll
    for (int n = 0; n < 4; n++) {
      const int col  = n0 + wn * 64 + n * 16 + (lane & 15);
      const int rowb = m0 + wm * 64 + m * 16 + (lane >> 4) * 4;
#pragma unroll
      for (int j = 0; j < 4; j++) {
        const int row  = rowb + j;
        const int idxv = indices[row * 512 + (col >> 3)];
        const float cv = centroids[idxv * 8 + (col & 7)];
        const float w  = cv * wscale[row] + wbias[row] + acc[m][n][j];
        Cb[(size_t)row * N + col] = __float2bfloat16(w);
      }
    }
  }
}

// ---------------- main 256x256 pipelined GEMM ----------------
// R4 sync structure (proven race-free) + R5 addressing opts:
//  * 2-tile manual unroll -> buffer offsets are literals -> ds_read base+imm
//  * running global pointers for stages (no per-tile k math, no wrap)
//  * per-tile wait vmcnt(4): queue at t.p3 = [(t-1).p1, (t-1).p2, (t-1).p3,
//    t.p0, t.p1, t.p2] x2 = 12; end-of-p3 loads need <= t.p0 landed -> 4.
//    (vmcnt(6) leaves B0B1(t+1) in flight -> R5's race. Do NOT loosen.)
__global__ __launch_bounds__(512, 2) void gemm256(const bf16* __restrict__ A,
                                                  const bf16* __restrict__ B,
                                                  float* __restrict__ C,
                                                  const float* __restrict__ bias)
{
  extern __shared__ char smem[];     // [2][A 32KB | B 32KB] = 128 KiB
  constexpr int K = 4096;
  constexpr int N = 4096;

  const int tid  = threadIdx.x;
  const int lane = tid & 63;
  const int wave = tid >> 6;
  const int wm   = wave >> 2;        // 0..1
  const int wn   = wave & 3;         // 0..3
  const int fr   = lane & 15;
  const int kk   = (lane >> 4) * 8;
  const int swx  = (fr & 7) << 4;    // read-side swizzle

  // XCD-aware swizzle, 8x8 tile group per XCD: grid m=32, n=16
  const int bid = blockIdx.x;
  const int xcd = bid & 7;
  const int idx = bid >> 3;
  const int mi  = (xcd & 3) * 8 + (idx & 7);
  const int ni  = (xcd >> 2) * 8 + (idx >> 3);
  const int m0  = mi * 256;
  const int n0  = ni * 256;

  // stage bases: inverse-swizzled global source for linear global_load_lds dest.
  const int pA = tid * 16;
  const int rA = pA >> 7;
  const int kA = ((pA ^ ((rA & 7) << 4)) & 127) >> 1;
  const bf16* gA0 = A + (size_t)(m0 + rA) * K + kA;
  const int pB = (tid >> 8) * 8192 + (tid & 255) * 16;
  const int rB = pB >> 7;
  const int kB = ((pB ^ ((rB & 7) << 4)) & 127) >> 1;
  const bf16* gB0 = B + (size_t)(n0 + rB) * K + kB;

  f32x4 acc[8][4] = {};

  // slot (rowdelta, lds-byte-delta): A: s0(0,0) s1(128,16384) s2(64,8192) s3(192,24576)
  //                                  B: s0(0,0) s1(128,16384) s2(32,4096) s3(160,20480)
  // gA_p tracks tile t+2's k for A stages; gB_p tracks tile t+1's k (B2/B3: +64).
#define STG_A0(bo) GLD_LDS16(gA_p,                   smem + (bo) + pA)
#define STG_A1(bo) GLD_LDS16(gA_p + 128 * 4096,      smem + (bo) + pA + 16384)
#define STG_A2(bo) GLD_LDS16(gA_p +  64 * 4096,      smem + (bo) + pA + 8192)
#define STG_A3(bo) GLD_LDS16(gA_p + 192 * 4096,      smem + (bo) + pA + 24576)
#define STG_B0(bo) GLD_LDS16(gB_p,                   smem + (bo) + 32768 + pB)
#define STG_B1(bo) GLD_LDS16(gB_p + 128 * 4096,      smem + (bo) + 32768 + pB + 16384)
#define STG_B2(bo) GLD_LDS16(gB_p + 64 +  32 * 4096, smem + (bo) + 32768 + pB + 4096)
#define STG_B3(bo) GLD_LDS16(gB_p + 64 + 160 * 4096, smem + (bo) + 32768 + pB + 20480)

#define LOAD_AQ(dst, qm, bo)                                                        \
  _Pragma("unroll") for (int mm = 0; mm < 4; mm++)                                  \
    _Pragma("unroll") for (int ks = 0; ks < 2; ks++)                                \
      dst[mm][ks] = *(const bf16x8*)(smem + (bo) +                                  \
          ((((wm * 128 + (qm) * 64 + mm * 16 + fr) * 128) +                         \
            (ks * 32 + kk) * 2) ^ swx));

#define LOAD_BQ(dst, qn, bo)                                                        \
  _Pragma("unroll") for (int nn = 0; nn < 2; nn++)                                  \
    _Pragma("unroll") for (int ks = 0; ks < 2; ks++)                                \
      dst[nn][ks] = *(const bf16x8*)(smem + (bo) + 32768 +                          \
          ((((wn * 64 + (qn) * 32 + nn * 16 + fr) * 128) +                          \
            (ks * 32 + kk) * 2) ^ swx));

#define CLUSTER(qm, qn, av, bv)                                                     \
  __builtin_amdgcn_s_setprio(1);                                                    \
  _Pragma("unroll") for (int ks = 0; ks < 2; ks++)                                  \
    _Pragma("unroll") for (int mm = 0; mm < 4; mm++)                                \
      _Pragma("unroll") for (int nn = 0; nn < 2; nn++)                              \
        acc[(qm) * 4 + mm][(qn) * 2 + nn] =                                         \
            __builtin_amdgcn_mfma_f32_16x16x32_bf16(                                \
                av[mm][ks], bv[nn][ks], acc[(qm) * 4 + mm][(qn) * 2 + nn],          \
                0, 0, 0);                                                           \
  __builtin_amdgcn_s_setprio(0);

#define SBAR   __builtin_amdgcn_s_barrier()
#define SCHED0 __builtin_amdgcn_sched_barrier(0)
#define VM4    asm volatile("s_waitcnt vmcnt(4)" ::: "memory")

  bf16x8 aq0[4][2], aq1[4][2], b0[2][2], b1[2][2], b0r[2][2];

  // prologue: tile0 all 8 slots -> buf0; tile1 (k=64) A0A1/B2B3/A2A3 -> buf1.
  // vmcnt(6) leaves exactly tile1's 6 loads in flight -> tile0's 8 landed.
  GLD_LDS16(gA0,                  smem + pA);
  GLD_LDS16(gA0 + 128 * 4096,     smem + pA + 16384);
  GLD_LDS16(gB0,                  smem + 32768 + pB);
  GLD_LDS16(gB0 + 128 * 4096,     smem + 32768 + pB + 16384);
  GLD_LDS16(gB0 +  32 * 4096,     smem + 32768 + pB + 4096);
  GLD_LDS16(gB0 + 160 * 4096,     smem + 32768 + pB + 20480);
  GLD_LDS16(gA0 +  64 * 4096,     smem + pA + 8192);
  GLD_LDS16(gA0 + 192 * 4096,     smem + pA + 24576);
  GLD_LDS16(gA0 + 64,             smem + 65536 + pA);
  GLD_LDS16(gA0 + 64 + 128 * 4096, smem + 65536 + pA + 16384);
  GLD_LDS16(gB0 + 64 +  32 * 4096, smem + 65536 + 32768 + pB + 4096);
  GLD_LDS16(gB0 + 64 + 160 * 4096, smem + 65536 + 32768 + pB + 20480);
  GLD_LDS16(gA0 + 64 +  64 * 4096, smem + 65536 + pA + 8192);
  GLD_LDS16(gA0 + 64 + 192 * 4096, smem + 65536 + pA + 24576);
  asm volatile("s_waitcnt vmcnt(6)" ::: "memory");
  SBAR;
  LOAD_AQ(aq0, 0, 0);
  LOAD_BQ(b0, 0, 0);
  SCHED0;

  const bf16* gA_p = gA0 + 128;        // tile t+2 (t=0) k offset
  const bf16* gB_p = gB0 + 64;         // tile t+1 (t=0) k offset

#define TILE(AB, NB)                                                                \
  {                                                                                 \
    /* p0 (qm0,qn0): stage B0B1(t+1)->NB; pre-load b1 (B2B3 of t) */                \
    SBAR;                                                                           \
    STG_B0(NB); STG_B1(NB);                                                         \
    LOAD_BQ(b1, 1, AB);                                                             \
    SCHED0;                                                                         \
    CLUSTER(0, 0, aq0, b0);                                                         \
    SCHED0;                                                                         \
    /* p1 (qm0,qn1): stage A0A1(t+2)->AB; post-load aq1 (A2A3 of t) */              \
    SBAR;                                                                           \
    STG_A0(AB); STG_A1(AB);                                                         \
    SCHED0;                                                                         \
    CLUSTER(0, 1, aq0, b1);                                                         \
    SCHED0;                                                                         \
    LOAD_AQ(aq1, 1, AB);                                                            \
    SCHED0;                                                                         \
    /* p2 (qm1,qn1): stage B2B3(t+2)->AB; pre-load b0r (B0B1 of t) */               \
    SBAR;                                                                           \
    STG_B2(AB); STG_B3(AB);                                                         \
    LOAD_BQ(b0r, 0, AB);                                                            \
    SCHED0;                                                                         \
    CLUSTER(1, 1, aq1, b1);                                                         \
    SCHED0;                                                                         \
    /* p3 (qm1,qn0): vmcnt(4) forces <= t.p0 landed; post-load next tile's aq0,b0 */\
    VM4;                                                                            \
    SBAR;                                                                           \
    STG_A2(AB); STG_A3(AB);                                                         \
    SCHED0;                                                                         \
    CLUSTER(1, 0, aq1, b0r);                                                        \
    SCHED0;                                                                         \
    LOAD_AQ(aq0, 0, NB);                                                            \
    LOAD_BQ(b0, 0, NB);                                                             \
    SCHED0;                                                                         \
    gA_p += 64; gB_p += 64;                                                         \
  }

  for (int tt = 0; tt < 32; tt++) {
    TILE(0, 65536);
    TILE(65536, 0);
  }

  // epilogue: C/D layout col = lane&15, row = (lane>>4)*4 + j
#pragma unroll
  for (int mf = 0; mf < 8; mf++) {
#pragma unroll
    for (int nf = 0; nf < 4; nf++) {
      const int col  = n0 + wn * 64 + nf * 16 + fr;
      const int row0 = m0 + wm * 128 + mf * 16 + (lane >> 4) * 4;
      const float bv = bias[col];
#pragma unroll
      for (int j = 0; j < 4; j++)
        C[(size_t)(row0 + j) * N + col] = acc[mf][nf][j] + bv;
    }
  }
#undef TILE
#undef CLUSTER
#undef LOAD_AQ
#undef LOAD_BQ
#undef SBAR
#undef SCHED0
#undef VM4
#undef STG_A0
#undef STG_A1
#undef STG_A2
#undef STG_A3
#undef STG_B0
#undef STG_B1
#undef STG_B2
#undef STG_B3
}

extern "C" void kernel_launch(void* const* d_in, const int* in_sizes, int n_in,
                              void* d_out, int out_size, void* d_ws, size_t ws_size,
                              hipStream_t stream)
{
  const float* x         = (const float*)d_in[0];
  const float* centroids = (const float*)d_in[1];
  const int*   indices   = (const int*)d_in[2];
  const float* U         = (const float*)d_in[3];
  const float* S         = (const float*)d_in[4];
  const float* Vt        = (const float*)d_in[5];
  const float* wscale    = (const float*)d_in[6];
  const float* wbias     = (const float*)d_in[7];
  const float* bias      = (const float*)d_in[8];
  float* out = (float*)d_out;

  char* ws = (char*)d_ws;
  bf16* xb   = (bf16*)(ws);                          // 64 MB
  bf16* Wb   = (bf16*)(ws + 67108864);               // 32 MB
  bf16* Ub   = (bf16*)(ws + 100663296);              // 1 MB
  bf16* SVtT = (bf16*)(ws + 101711872);              // 1 MB

  convert_x_kernel<<<2048, 256, 0, stream>>>(x, xb, 8192 * 4096);
  prep_kernel<<<2048, 256, 0, stream>>>(U, S, Vt, Ub, SVtT);

  // W[o][i] = codebook(o,i)*wscale[o] + wbias[o] + sum_r Ub[o][r]*SVtT[i][r]
  dim3 gW(4096 / 128, 4096 / 128);
  gemm_wbuild<<<gW, 256, 0, stream>>>(Ub, SVtT, Wb, 4096, 4096, 128,
                                      indices, centroids, wscale, wbias);

  // out[t][o] = sum_i xb[t][i]*Wb[o][i] + bias[o]
  gemm256<<<512, 512, 131072, stream>>>(xb, Wb, out, bias);
}